// Round 3
// baseline (1439.080 us; speedup 1.0000x reference)
//
#include <hip/hip_runtime.h>
#include <math.h>

typedef unsigned short u16;
typedef unsigned int u32;

__device__ __forceinline__ float bf2f(u16 u) {
  union { u32 i; float f; } v; v.i = ((u32)u) << 16; return v.f;
}
__device__ __forceinline__ u16 f2bf(float f) {
  union { float f; u32 i; } v; v.f = f;
  u32 i = v.i;
  i += 0x7fffu + ((i >> 16) & 1u);   // round-to-nearest-even
  return (u16)(i >> 16);
}

// dtype-polymorphic loads (F32: inputs are float32; else bf16 bits)
template<bool F32>
__device__ __forceinline__ float ld(const void* p, int i) {
  if (F32) return ((const float*)p)[i];
  return bf2f(((const u16*)p)[i]);
}
template<bool F32>
__device__ __forceinline__ void ld4(const void* p, int i4,
                                    float& a, float& b, float& c, float& d) {
  if (F32) {
    const float4 v = ((const float4*)p)[i4];
    a = v.x; b = v.y; c = v.z; d = v.w;
  } else {
    const ushort4 v = ((const ushort4*)p)[i4];
    a = bf2f(v.x); b = bf2f(v.y); c = bf2f(v.z); d = bf2f(v.w);
  }
}

#define NQUAD 131072  // (2*64^3)/4 token-quads

// ---------------------------------------------------------------------------
// Kernel 0: detect input dtype. Low u16 of each 32-bit word: genuine bf16
// value (exp field in [90,150]) if bf16-packed; mantissa noise (or zeros, if
// values are bf16-rounded fp32) otherwise.
// ---------------------------------------------------------------------------
__global__ __launch_bounds__(64)
void detect_kernel(const void* __restrict__ xv, int* __restrict__ flag) {
  const u32* xw = (const u32*)xv;
  const int t = threadIdx.x;
  int bad = 0;
  for (int i = t; i < 1024; i += 64) {
    const int e = (int)((xw[i] >> 7) & 0xFF);  // exponent field of low u16 as bf16
    if (e < 90 || e > 150) bad++;
  }
#pragma unroll
  for (int m = 1; m < 64; m <<= 1) bad += __shfl_xor(bad, m);
  if (t == 0) *flag = (bad > 256) ? 1 : 0;  // fp32 -> ~770+ bad; bf16 -> ~0
}

// ---------------------------------------------------------------------------
// Kernel 1: LN1 + shifted-window attention + proj + residual -> out (f32 x1)
// One wave per window (65536 windows). aO overlays ln (dead after QKV).
// ---------------------------------------------------------------------------
template<bool F32>
__device__ __forceinline__ void attn_body(
    const void* __restrict__ x,
    const void* __restrict__ n1g, const void* __restrict__ n1b,
    const void* __restrict__ qkvw, const void* __restrict__ qkvb,
    const void* __restrict__ rpb,
    const void* __restrict__ projw, const void* __restrict__ projb,
    float* __restrict__ out,
    float* __restrict__ ln, float* __restrict__ qL,
    float* __restrict__ kL, float* __restrict__ vL)
{
  const int win  = blockIdx.x;
  const int b    = win >> 15;
  const int widx = win & 32767;
  const int wz = widx >> 10, wy = (widx >> 5) & 31, wx = widx & 31;
  const int t = threadIdx.x;

  // ---- load 8 tokens (shifted-frame -> source coords) + LayerNorm1 ----
  const float g1 = ld<F32>(n1g, t), be1 = ld<F32>(n1b, t);
#pragma unroll
  for (int s = 0; s < 8; ++s) {
    const int i = (s >> 2) & 1, j = (s >> 1) & 1, k = s & 1;
    const int od = (2*wz + i + 1) & 63;   // roll(-1): shifted coord c reads c+1
    const int oh = (2*wy + j + 1) & 63;
    const int ow = (2*wx + k + 1) & 63;
    const int lsrc = (od << 12) | (oh << 6) | ow;
    const float v = ld<F32>(x, ((b << 18) + lsrc) * 64 + t);
    float s1 = v, sq = v * v;
#pragma unroll
    for (int m = 1; m < 64; m <<= 1) {
      s1 += __shfl_xor(s1, m);
      sq += __shfl_xor(sq, m);
    }
    const float mu  = s1 * 0.015625f;
    const float var = sq * 0.015625f - mu * mu;
    ln[s*64 + t] = (v - mu) * rsqrtf(var + 1e-5f) * g1 + be1;
  }
  __syncthreads();

  // ---- QKV projection: thread t owns output feature t of q/k/v ----
  float aq[8], ak[8], av[8];
#pragma unroll
  for (int s = 0; s < 8; ++s) { aq[s] = 0.f; ak[s] = 0.f; av[s] = 0.f; }
  for (int kc = 0; kc < 64; ++kc) {
    const float wq = ld<F32>(qkvw, kc*192 + t);
    const float wk = ld<F32>(qkvw, kc*192 + 64 + t);
    const float wv = ld<F32>(qkvw, kc*192 + 128 + t);
#pragma unroll
    for (int s = 0; s < 8; ++s) {
      const float lv = ln[s*64 + kc];
      aq[s] += lv * wq; ak[s] += lv * wk; av[s] += lv * wv;
    }
  }
  {
    const float bq = ld<F32>(qkvb, t), bk = ld<F32>(qkvb, 64 + t),
                bv = ld<F32>(qkvb, 128 + t);
#pragma unroll
    for (int s = 0; s < 8; ++s) {
      qL[s*64 + t] = (aq[s] + bq) * 0.35355339059327373f;  // scale after bias
      kL[s*64 + t] = ak[s] + bk;
      vL[s*64 + t] = av[s] + bv;
    }
  }
  __syncthreads();

  // ---- attention: thread = (head hh, query row qi) ----
  const int hh = t >> 3, qi = t & 7;
  float qr[8];
#pragma unroll
  for (int d = 0; d < 8; ++d) qr[d] = qL[qi*64 + hh*8 + d];
  float sc[8];
#pragma unroll
  for (int kk = 0; kk < 8; ++kk) {
    float a = 0.f;
#pragma unroll
    for (int d = 0; d < 8; ++d) a += qr[d] * kL[kk*64 + hh*8 + d];
    sc[kk] = a;
  }
  // bug-faithful relative-position bias: bias[h][q][k] = rpb[REL[h*8+q], k]
  {
    const int rel = 3 * (((hh>>1)&1) - ((qi>>1)&1) + 1)
                  +     (((hh>>2)&1) - ((qi>>2)&1) + 1)
                  +     (( hh    &1) - ( qi    &1) + 1);
#pragma unroll
    for (int kk = 0; kk < 8; ++kk) sc[kk] += ld<F32>(rpb, rel*8 + kk);
  }
  // shifted-window mask (regions on shifted-frame coords: <62 / 62 / 63)
  {
    int cnts[8];
#pragma unroll
    for (int p = 0; p < 8; ++p) {
      const int sd = 2*wz + ((p>>2)&1);
      const int sh = 2*wy + ((p>>1)&1);
      const int sw = 2*wx + (p&1);
      const int rd = sd >= 62 ? sd - 61 : 0;
      const int rh = sh >= 62 ? sh - 61 : 0;
      const int rw = sw >= 62 ? sw - 61 : 0;
      cnts[p] = rd*9 + rh*3 + rw;
    }
#pragma unroll
    for (int kk = 0; kk < 8; ++kk)
      if (cnts[kk] != cnts[qi]) sc[kk] -= 100.f;
  }
  // softmax over kk
  float mx = sc[0];
#pragma unroll
  for (int kk = 1; kk < 8; ++kk) mx = fmaxf(mx, sc[kk]);
  float pr[8], lsum = 0.f;
#pragma unroll
  for (int kk = 0; kk < 8; ++kk) { pr[kk] = expf(sc[kk] - mx); lsum += pr[kk]; }
  const float inv = 1.f / lsum;
#pragma unroll
  for (int d = 0; d < 8; ++d) {
    float o = 0.f;
#pragma unroll
    for (int kk = 0; kk < 8; ++kk) o += pr[kk] * vL[kk*64 + hh*8 + d];
    ln[qi*64 + hh*8 + d] = o * inv;   // aO overlays ln
  }
  __syncthreads();

  // ---- proj + residual through the bug-faithful window reverse ----
  float acc[8];
#pragma unroll
  for (int s = 0; s < 8; ++s) acc[s] = 0.f;
  for (int kc = 0; kc < 64; ++kc) {
    const float w = ld<F32>(projw, kc*64 + t);
#pragma unroll
    for (int s = 0; s < 8; ++s) acc[s] += ln[s*64 + kc] * w;
  }
  const float pb = ld<F32>(projb, t);
  const int fd = (2*wz + ((wy>>3)&1) + 1) & 63;            // includes roll(+1)
  const int Hb = 8*(wy&7) + 4*(wx>>4) + (wy>>4);
  const int Wb = 4*(wx&15);
#pragma unroll
  for (int s = 0; s < 8; ++s) {
    const int i = (s>>2)&1, j = (s>>1)&1, k = s&1;
    const int fh = (Hb + 2*j + 1) & 63;
    const int fw = (Wb + 2*i + k + 1) & 63;
    const int off = ((b << 18) + ((fd<<12)|(fh<<6)|fw)) * 64 + t;
    out[off] = ld<F32>(x, off) + acc[s] + pb;   // fp32 output
  }
}

__global__ __launch_bounds__(64)
void attn_kernel(const void* __restrict__ x,
                 const void* __restrict__ n1g, const void* __restrict__ n1b,
                 const void* __restrict__ qkvw, const void* __restrict__ qkvb,
                 const void* __restrict__ rpb,
                 const void* __restrict__ projw, const void* __restrict__ projb,
                 const int* __restrict__ flag, float* __restrict__ out)
{
  __shared__ float ln[8*64], qL[8*64], kL[8*64], vL[8*64];
  if (*flag)
    attn_body<true >(x, n1g, n1b, qkvw, qkvb, rpb, projw, projb, out, ln, qL, kL, vL);
  else
    attn_body<false>(x, n1g, n1b, qkvw, qkvb, rpb, projw, projb, out, ln, qL, kL, vL);
}

// ---------------------------------------------------------------------------
// Kernel 2: LN2 + MLP(64->256 GELU ->64) + residual, in-place on io (fp32).
// 256 threads = 4 waves; each wave 4 tokens/iter. w2 transposed into LDS.
// ---------------------------------------------------------------------------
template<bool F32>
__device__ __forceinline__ void mlp_body(
    float* __restrict__ io,
    const void* __restrict__ n2g, const void* __restrict__ n2b,
    const void* __restrict__ mw1, const void* __restrict__ mb1,
    const void* __restrict__ mw2, const void* __restrict__ mb2,
    u16* __restrict__ w2T, float* __restrict__ lnv, u16* __restrict__ hv)
{
  const int tid = threadIdx.x;
  for (int e = tid; e < 16384; e += 256) {
    const u16 w = F32 ? f2bf(((const float*)mw2)[e]) : ((const u16*)mw2)[e];
    w2T[(e & 63) * 260 + (e >> 6)] = w;   // w2T[c*260+j] = w2[j*64+c]
  }
  __syncthreads();

  const int wave = tid >> 6, lane = tid & 63;
  const float g2 = ld<F32>(n2g, lane), be2 = ld<F32>(n2b, lane);
  float b1v[4];
#pragma unroll
  for (int q = 0; q < 4; ++q) b1v[q] = ld<F32>(mb1, 4*lane + q);
  const float b2v = ld<F32>(mb2, lane);

  for (int base = blockIdx.x * 4; base < NQUAD; base += gridDim.x * 4) {
    const int tok0 = (base + wave) * 4;
    float* xp = io + (size_t)tok0 * 64;

    float skip[4];
#pragma unroll
    for (int tt = 0; tt < 4; ++tt) skip[tt] = xp[tt*64 + lane];
#pragma unroll
    for (int tt = 0; tt < 4; ++tt) {
      const float v = skip[tt];
      float s1 = v, sq = v * v;
#pragma unroll
      for (int m = 1; m < 64; m <<= 1) {
        s1 += __shfl_xor(s1, m);
        sq += __shfl_xor(sq, m);
      }
      const float mu  = s1 * 0.015625f;
      const float var = sq * 0.015625f - mu * mu;
      lnv[(wave*4 + tt)*64 + lane] = (v - mu) * rsqrtf(var + 1e-5f) * g2 + be2;
    }
    __syncthreads();

    // phase 1: hidden = ln @ w1 ; lane owns j = 4*lane..4*lane+3
    float acc[4][4];
#pragma unroll
    for (int tt = 0; tt < 4; ++tt)
#pragma unroll
      for (int q = 0; q < 4; ++q) acc[tt][q] = 0.f;
#pragma unroll 4
    for (int c = 0; c < 64; ++c) {
      float w0, w1f, w2f, w3f;
      ld4<F32>(mw1, c*64 + lane, w0, w1f, w2f, w3f);  // w1[c][4*lane+q]
#pragma unroll
      for (int tt = 0; tt < 4; ++tt) {
        const float lv = lnv[(wave*4 + tt)*64 + c];
        acc[tt][0] += lv*w0; acc[tt][1] += lv*w1f;
        acc[tt][2] += lv*w2f; acc[tt][3] += lv*w3f;
      }
    }
    // exact GELU, stash hidden as bf16
#pragma unroll
    for (int tt = 0; tt < 4; ++tt) {
      ushort4 h4; float h;
      h = acc[tt][0] + b1v[0]; h4.x = f2bf(0.5f*h*(1.f + erff(h*0.70710678118654752f)));
      h = acc[tt][1] + b1v[1]; h4.y = f2bf(0.5f*h*(1.f + erff(h*0.70710678118654752f)));
      h = acc[tt][2] + b1v[2]; h4.z = f2bf(0.5f*h*(1.f + erff(h*0.70710678118654752f)));
      h = acc[tt][3] + b1v[3]; h4.w = f2bf(0.5f*h*(1.f + erff(h*0.70710678118654752f)));
      ((ushort4*)(hv + (wave*4 + tt)*256))[lane] = h4;
    }
    __syncthreads();

    // phase 2: out = hidden @ w2 ; lane owns output channel lane
    float o[4] = {0.f, 0.f, 0.f, 0.f};
#pragma unroll 4
    for (int jq = 0; jq < 64; ++jq) {
      const ushort4 wv = *(const ushort4*)&w2T[lane*260 + 4*jq];
      const float w0 = bf2f(wv.x), w1f = bf2f(wv.y), w2f = bf2f(wv.z), w3f = bf2f(wv.w);
#pragma unroll
      for (int tt = 0; tt < 4; ++tt) {
        const ushort4 h4 = ((const ushort4*)(hv + (wave*4 + tt)*256))[jq];
        o[tt] += bf2f(h4.x)*w0 + bf2f(h4.y)*w1f + bf2f(h4.z)*w2f + bf2f(h4.w)*w3f;
      }
    }
#pragma unroll
    for (int tt = 0; tt < 4; ++tt)
      xp[tt*64 + lane] = skip[tt] + o[tt] + b2v;   // fp32 output
    __syncthreads();
  }
}

__global__ __launch_bounds__(256)
void mlp_kernel(float* __restrict__ io,
                const void* __restrict__ n2g, const void* __restrict__ n2b,
                const void* __restrict__ mw1, const void* __restrict__ mb1,
                const void* __restrict__ mw2, const void* __restrict__ mb2,
                const int* __restrict__ flag)
{
  __shared__ __align__(16) u16 w2T[64 * 260];
  __shared__ __align__(16) float lnv[16 * 64];
  __shared__ __align__(16) u16 hv[16 * 256];
  if (*flag)
    mlp_body<true >(io, n2g, n2b, mw1, mb1, mw2, mb2, w2T, lnv, hv);
  else
    mlp_body<false>(io, n2g, n2b, mw1, mb1, mw2, mb2, w2T, lnv, hv);
}

extern "C" void kernel_launch(void* const* d_in, const int* in_sizes, int n_in,
                              void* d_out, int out_size, void* d_ws, size_t ws_size,
                              hipStream_t stream) {
  const void* x     = d_in[0];
  const void* n1g   = d_in[1];
  const void* n1b   = d_in[2];
  const void* qkvw  = d_in[3];
  const void* qkvb  = d_in[4];
  const void* rpb   = d_in[5];
  const void* projw = d_in[6];
  const void* projb = d_in[7];
  const void* n2g   = d_in[8];
  const void* n2b   = d_in[9];
  const void* mw1   = d_in[10];
  const void* mb1   = d_in[11];
  const void* mw2   = d_in[12];
  const void* mb2   = d_in[13];
  float* out = (float*)d_out;
  int* flag  = (int*)d_ws;

  detect_kernel<<<dim3(1), dim3(64), 0, stream>>>(x, flag);
  attn_kernel<<<dim3(65536), dim3(64), 0, stream>>>(
      x, n1g, n1b, qkvw, qkvb, rpb, projw, projb, flag, out);
  mlp_kernel<<<dim3(768), dim3(256), 0, stream>>>(
      out, n2g, n2b, mw1, mb1, mw2, mb2, flag);
}

// Round 4
// 827.291 us; speedup vs baseline: 1.7395x; 1.7395x over previous
//
#include <hip/hip_runtime.h>
#include <math.h>

typedef unsigned short u16;
typedef unsigned int u32;
typedef __attribute__((ext_vector_type(8))) short short8;   // 8 bf16 (4 VGPRs)
typedef __attribute__((ext_vector_type(4))) float f32x4;

__device__ __forceinline__ float bf2f(u16 u) {
  union { u32 i; float f; } v; v.i = ((u32)u) << 16; return v.f;
}
__device__ __forceinline__ u16 f2bf(float f) {
  union { float f; u32 i; } v; v.f = f;
  u32 i = v.i;
  i += 0x7fffu + ((i >> 16) & 1u);   // round-to-nearest-even
  return (u16)(i >> 16);
}

// dtype-polymorphic loads (F32: inputs are float32; else bf16 bits)
template<bool F32>
__device__ __forceinline__ float ld(const void* p, int i) {
  if (F32) return ((const float*)p)[i];
  return bf2f(((const u16*)p)[i]);
}

// ---------------------------------------------------------------------------
// Kernel 0: detect input dtype (fp32 vs bf16-packed). See round-2 notes.
// ---------------------------------------------------------------------------
__global__ __launch_bounds__(64)
void detect_kernel(const void* __restrict__ xv, int* __restrict__ flag) {
  const u32* xw = (const u32*)xv;
  const int t = threadIdx.x;
  int bad = 0;
  for (int i = t; i < 1024; i += 64) {
    const int e = (int)((xw[i] >> 7) & 0xFF);
    if (e < 90 || e > 150) bad++;
  }
#pragma unroll
  for (int m = 1; m < 64; m <<= 1) bad += __shfl_xor(bad, m);
  if (t == 0) *flag = (bad > 256) ? 1 : 0;
}

// ---------------------------------------------------------------------------
// Kernel 1: LN1 + shifted-window attention + proj + residual -> out (f32 x1)
// One wave per window (65536 windows). Unchanged from round 3 (passing).
// ---------------------------------------------------------------------------
template<bool F32>
__device__ __forceinline__ void attn_body(
    const void* __restrict__ x,
    const void* __restrict__ n1g, const void* __restrict__ n1b,
    const void* __restrict__ qkvw, const void* __restrict__ qkvb,
    const void* __restrict__ rpb,
    const void* __restrict__ projw, const void* __restrict__ projb,
    float* __restrict__ out,
    float* __restrict__ ln, float* __restrict__ qL,
    float* __restrict__ kL, float* __restrict__ vL)
{
  const int win  = blockIdx.x;
  const int b    = win >> 15;
  const int widx = win & 32767;
  const int wz = widx >> 10, wy = (widx >> 5) & 31, wx = widx & 31;
  const int t = threadIdx.x;

  const float g1 = ld<F32>(n1g, t), be1 = ld<F32>(n1b, t);
#pragma unroll
  for (int s = 0; s < 8; ++s) {
    const int i = (s >> 2) & 1, j = (s >> 1) & 1, k = s & 1;
    const int od = (2*wz + i + 1) & 63;
    const int oh = (2*wy + j + 1) & 63;
    const int ow = (2*wx + k + 1) & 63;
    const int lsrc = (od << 12) | (oh << 6) | ow;
    const float v = ld<F32>(x, ((b << 18) + lsrc) * 64 + t);
    float s1 = v, sq = v * v;
#pragma unroll
    for (int m = 1; m < 64; m <<= 1) {
      s1 += __shfl_xor(s1, m);
      sq += __shfl_xor(sq, m);
    }
    const float mu  = s1 * 0.015625f;
    const float var = sq * 0.015625f - mu * mu;
    ln[s*64 + t] = (v - mu) * rsqrtf(var + 1e-5f) * g1 + be1;
  }
  __syncthreads();

  float aq[8], ak[8], av[8];
#pragma unroll
  for (int s = 0; s < 8; ++s) { aq[s] = 0.f; ak[s] = 0.f; av[s] = 0.f; }
  for (int kc = 0; kc < 64; ++kc) {
    const float wq = ld<F32>(qkvw, kc*192 + t);
    const float wk = ld<F32>(qkvw, kc*192 + 64 + t);
    const float wv = ld<F32>(qkvw, kc*192 + 128 + t);
#pragma unroll
    for (int s = 0; s < 8; ++s) {
      const float lv = ln[s*64 + kc];
      aq[s] += lv * wq; ak[s] += lv * wk; av[s] += lv * wv;
    }
  }
  {
    const float bq = ld<F32>(qkvb, t), bk = ld<F32>(qkvb, 64 + t),
                bv = ld<F32>(qkvb, 128 + t);
#pragma unroll
    for (int s = 0; s < 8; ++s) {
      qL[s*64 + t] = (aq[s] + bq) * 0.35355339059327373f;
      kL[s*64 + t] = ak[s] + bk;
      vL[s*64 + t] = av[s] + bv;
    }
  }
  __syncthreads();

  const int hh = t >> 3, qi = t & 7;
  float qr[8];
#pragma unroll
  for (int d = 0; d < 8; ++d) qr[d] = qL[qi*64 + hh*8 + d];
  float sc[8];
#pragma unroll
  for (int kk = 0; kk < 8; ++kk) {
    float a = 0.f;
#pragma unroll
    for (int d = 0; d < 8; ++d) a += qr[d] * kL[kk*64 + hh*8 + d];
    sc[kk] = a;
  }
  {
    const int rel = 3 * (((hh>>1)&1) - ((qi>>1)&1) + 1)
                  +     (((hh>>2)&1) - ((qi>>2)&1) + 1)
                  +     (( hh    &1) - ( qi    &1) + 1);
#pragma unroll
    for (int kk = 0; kk < 8; ++kk) sc[kk] += ld<F32>(rpb, rel*8 + kk);
  }
  {
    int cnts[8];
#pragma unroll
    for (int p = 0; p < 8; ++p) {
      const int sd = 2*wz + ((p>>2)&1);
      const int sh = 2*wy + ((p>>1)&1);
      const int sw = 2*wx + (p&1);
      const int rd = sd >= 62 ? sd - 61 : 0;
      const int rh = sh >= 62 ? sh - 61 : 0;
      const int rw = sw >= 62 ? sw - 61 : 0;
      cnts[p] = rd*9 + rh*3 + rw;
    }
#pragma unroll
    for (int kk = 0; kk < 8; ++kk)
      if (cnts[kk] != cnts[qi]) sc[kk] -= 100.f;
  }
  float mx = sc[0];
#pragma unroll
  for (int kk = 1; kk < 8; ++kk) mx = fmaxf(mx, sc[kk]);
  float pr[8], lsum = 0.f;
#pragma unroll
  for (int kk = 0; kk < 8; ++kk) { pr[kk] = expf(sc[kk] - mx); lsum += pr[kk]; }
  const float inv = 1.f / lsum;
#pragma unroll
  for (int d = 0; d < 8; ++d) {
    float o = 0.f;
#pragma unroll
    for (int kk = 0; kk < 8; ++kk) o += pr[kk] * vL[kk*64 + hh*8 + d];
    ln[qi*64 + hh*8 + d] = o * inv;
  }
  __syncthreads();

  float acc[8];
#pragma unroll
  for (int s = 0; s < 8; ++s) acc[s] = 0.f;
  for (int kc = 0; kc < 64; ++kc) {
    const float w = ld<F32>(projw, kc*64 + t);
#pragma unroll
    for (int s = 0; s < 8; ++s) acc[s] += ln[s*64 + kc] * w;
  }
  const float pb = ld<F32>(projb, t);
  const int fd = (2*wz + ((wy>>3)&1) + 1) & 63;
  const int Hb = 8*(wy&7) + 4*(wx>>4) + (wy>>4);
  const int Wb = 4*(wx&15);
#pragma unroll
  for (int s = 0; s < 8; ++s) {
    const int i = (s>>2)&1, j = (s>>1)&1, k = s&1;
    const int fh = (Hb + 2*j + 1) & 63;
    const int fw = (Wb + 2*i + k + 1) & 63;
    const int off = ((b << 18) + ((fd<<12)|(fh<<6)|fw)) * 64 + t;
    out[off] = ld<F32>(x, off) + acc[s] + pb;
  }
}

__global__ __launch_bounds__(64)
void attn_kernel(const void* __restrict__ x,
                 const void* __restrict__ n1g, const void* __restrict__ n1b,
                 const void* __restrict__ qkvw, const void* __restrict__ qkvb,
                 const void* __restrict__ rpb,
                 const void* __restrict__ projw, const void* __restrict__ projb,
                 const int* __restrict__ flag, float* __restrict__ out)
{
  __shared__ float ln[8*64], qL[8*64], kL[8*64], vL[8*64];
  if (*flag)
    attn_body<true >(x, n1g, n1b, qkvw, qkvb, rpb, projw, projb, out, ln, qL, kL, vL);
  else
    attn_body<false>(x, n1g, n1b, qkvw, qkvb, rpb, projw, projb, out, ln, qL, kL, vL);
}

// ---------------------------------------------------------------------------
// Kernel 2 (MFMA rewrite): LN2 + MLP(64->256 GELU ->64) + residual, in-place.
// Block = 256 thr (4 waves), 64 tokens/chunk, 8192 chunks.
//   phase1: A_ln[64x64] @ W1[64x256]  (wave w owns cols w*64..w*64+63)
//   phase2: H[64x256]   @ W2[256x64]  (wave w owns cols w*16..w*16+15)
// Weights live in per-wave register fragments (preloaded once per block).
// MFMA layouts (verified m89/m120): A m=lane&15,k=quad*8+j; B n=lane&15,
// k=quad*8+j; C/D col=lane&15,row=quad*4+reg.
// ---------------------------------------------------------------------------
template<bool F32>
__device__ __forceinline__ void mlp_body(
    float* __restrict__ io,
    const void* __restrict__ n2g, const void* __restrict__ n2b,
    const void* __restrict__ mw1, const void* __restrict__ mb1,
    const void* __restrict__ mw2, const void* __restrict__ mb2,
    u16* __restrict__ aL, u16* __restrict__ hL)
{
  const int tid  = threadIdx.x;
  const int w    = tid >> 6, l = tid & 63;
  const int quad = l >> 4,  col = l & 15;

  const float g2 = ld<F32>(n2g, l), be2 = ld<F32>(n2b, l);

  // ---- preload W1/W2 B-fragments into registers (once per block) ----
  short8 b1f[2][4];                  // [kt][nt], phase1 cols w*64+nt*16+col
#pragma unroll
  for (int kt = 0; kt < 2; ++kt)
#pragma unroll
    for (int nt = 0; nt < 4; ++nt) {
      short8 f;
#pragma unroll
      for (int j = 0; j < 8; ++j) {
        const int k = kt*32 + quad*8 + j;
        const int n = w*64 + nt*16 + col;
        f[j] = (short)f2bf(ld<F32>(mw1, k*256 + n));
      }
      b1f[kt][nt] = f;
    }
  short8 b2f[8];                     // [kt], phase2 col w*16+col
#pragma unroll
  for (int kt = 0; kt < 8; ++kt) {
    short8 f;
#pragma unroll
    for (int j = 0; j < 8; ++j) {
      const int k = kt*32 + quad*8 + j;
      f[j] = (short)f2bf(ld<F32>(mw2, k*64 + w*16 + col));
    }
    b2f[kt] = f;
  }
  float b1v[4];
#pragma unroll
  for (int nt = 0; nt < 4; ++nt) b1v[nt] = ld<F32>(mb1, w*64 + nt*16 + col);
  const float b2v = ld<F32>(mb2, w*16 + col);

  for (int chunk = blockIdx.x; chunk < 8192; chunk += gridDim.x) {
    const int T0 = chunk * 64;

    // ---- LN2: wave w handles tokens T0+w*16 .. +15 (lane = channel) ----
#pragma unroll 4
    for (int t = 0; t < 16; ++t) {
      const int tok = T0 + w*16 + t;
      const float v = io[tok*64 + l];
      float s1 = v, sq = v * v;
#pragma unroll
      for (int m = 1; m < 64; m <<= 1) {
        s1 += __shfl_xor(s1, m);
        sq += __shfl_xor(sq, m);
      }
      const float mu  = s1 * 0.015625f;
      const float var = sq * 0.015625f - mu * mu;
      aL[(w*16 + t)*72 + l] = f2bf((v - mu) * rsqrtf(var + 1e-5f) * g2 + be2);
    }
    __syncthreads();

    // ---- phase 1: 64x64 @ 64x256 -> wave's 64x64 slab ----
    f32x4 acc[4][4];
#pragma unroll
    for (int mt = 0; mt < 4; ++mt)
#pragma unroll
      for (int nt = 0; nt < 4; ++nt) acc[mt][nt] = (f32x4){0.f,0.f,0.f,0.f};
#pragma unroll
    for (int kt = 0; kt < 2; ++kt) {
      short8 aF[4];
#pragma unroll
      for (int mt = 0; mt < 4; ++mt)
        aF[mt] = *(const short8*)&aL[(mt*16 + col)*72 + kt*32 + quad*8];
#pragma unroll
      for (int mt = 0; mt < 4; ++mt)
#pragma unroll
        for (int nt = 0; nt < 4; ++nt)
          acc[mt][nt] = __builtin_amdgcn_mfma_f32_16x16x32_bf16(
              aF[mt], b1f[kt][nt], acc[mt][nt], 0, 0, 0);
    }

    // ---- bias + exact GELU + pack bf16 -> H in LDS ----
#pragma unroll
    for (int mt = 0; mt < 4; ++mt)
#pragma unroll
      for (int nt = 0; nt < 4; ++nt)
#pragma unroll
        for (int r = 0; r < 4; ++r) {
          const float h = acc[mt][nt][r] + b1v[nt];
          const float g = 0.5f * h * (1.f + erff(h * 0.70710678118654752f));
          hL[(mt*16 + quad*4 + r)*264 + w*64 + nt*16 + col] = f2bf(g);
        }
    __syncthreads();

    // ---- phase 2: 64x256 @ 256x64 -> wave's 64x16 slab ----
    f32x4 acc2[4];
#pragma unroll
    for (int mt = 0; mt < 4; ++mt) acc2[mt] = (f32x4){0.f,0.f,0.f,0.f};
#pragma unroll
    for (int kt = 0; kt < 8; ++kt)
#pragma unroll
      for (int mt = 0; mt < 4; ++mt) {
        const short8 aF = *(const short8*)&hL[(mt*16 + col)*264 + kt*32 + quad*8];
        acc2[mt] = __builtin_amdgcn_mfma_f32_16x16x32_bf16(
            aF, b2f[kt], acc2[mt], 0, 0, 0);
      }

    // ---- residual read-modify-write (fp32, L2-hot) ----
#pragma unroll
    for (int mt = 0; mt < 4; ++mt)
#pragma unroll
      for (int r = 0; r < 4; ++r) {
        const int row = mt*16 + quad*4 + r;
        const int idx = (T0 + row)*64 + w*16 + col;
        io[idx] = io[idx] + acc2[mt][r] + b2v;
      }
    // no trailing barrier needed: phase-1 reads of aL are fenced by the
    // post-H __syncthreads; next-iter LN writes are safe.
  }
}

__global__ __launch_bounds__(256)
void mlp_kernel(float* __restrict__ io,
                const void* __restrict__ n2g, const void* __restrict__ n2b,
                const void* __restrict__ mw1, const void* __restrict__ mb1,
                const void* __restrict__ mw2, const void* __restrict__ mb2,
                const int* __restrict__ flag)
{
  __shared__ __align__(16) u16 aL[64 * 72];    //  9.2 KB, LN'd tokens (bf16)
  __shared__ __align__(16) u16 hL[64 * 264];   // 33.8 KB, hidden (bf16)
  if (*flag)
    mlp_body<true >(io, n2g, n2b, mw1, mb1, mw2, mb2, aL, hL);
  else
    mlp_body<false>(io, n2g, n2b, mw1, mb1, mw2, mb2, aL, hL);
}

extern "C" void kernel_launch(void* const* d_in, const int* in_sizes, int n_in,
                              void* d_out, int out_size, void* d_ws, size_t ws_size,
                              hipStream_t stream) {
  const void* x     = d_in[0];
  const void* n1g   = d_in[1];
  const void* n1b   = d_in[2];
  const void* qkvw  = d_in[3];
  const void* qkvb  = d_in[4];
  const void* rpb   = d_in[5];
  const void* projw = d_in[6];
  const void* projb = d_in[7];
  const void* n2g   = d_in[8];
  const void* n2b   = d_in[9];
  const void* mw1   = d_in[10];
  const void* mb1   = d_in[11];
  const void* mw2   = d_in[12];
  const void* mb2   = d_in[13];
  float* out = (float*)d_out;
  int* flag  = (int*)d_ws;

  detect_kernel<<<dim3(1), dim3(64), 0, stream>>>(x, flag);
  attn_kernel<<<dim3(65536), dim3(64), 0, stream>>>(
      x, n1g, n1b, qkvw, qkvb, rpb, projw, projb, flag, out);
  mlp_kernel<<<dim3(2048), dim3(256), 0, stream>>>(
      out, n2g, n2b, mw1, mb1, mw2, mb2, flag);
}